// Round 7
// baseline (74.645 us; speedup 1.0000x reference)
//
#include <hip/hip_runtime.h>

// B=256, F=32, N=16, D=512
//   sims[b,f,c,n] = relu(face[b,f]·ner[c,n])      (8192 x 4096 NT GEMM, K=512)
//   S_all[b,f]    = sum_{c,n} masked(sims)        (masked: ==1.0 -> 0)
//   pos[b,f]      = sum_n sims[b,f,b,n]           (unmasked diagonal)
//   diag_m[b,f]   = sum_n masked(sims[b,f,b,n])
//   loss = sum(relu((S_all-diag_m)/255 - pos + 0.2) * face_mask) / 256
//
// Round 7: r2's proven 128x128/BK=32/4-wave core + 3-buffer static LDS ring
// (48 KB), staging issued 2 K-tiles ahead, counted vmcnt(4) + ONE raw
// s_barrier per K-tile (never drain to 0 in loop). 3 blocks/CU co-resident.
// XCD-chunked block swizzle. Fused diag extraction + merged cvt kept.

#define DIM_D 512
#define M_TOT 8192
#define N_TOT 4096

typedef __attribute__((ext_vector_type(8))) short short8v;
typedef __attribute__((ext_vector_type(4))) float f32x4;

__device__ __forceinline__ unsigned short f2bf(float f) {
  unsigned int u = __builtin_bit_cast(unsigned int, f);
  u += 0x7fffu + ((u >> 16) & 1u);
  return (unsigned short)(u >> 16);
}

// ---------------------------------------------------------------------------
// Merged cvt: face+ner fp32 -> bf16, plus face_mask (fp32 row-sum != 0).
// ---------------------------------------------------------------------------
__global__ __launch_bounds__(256) void cvt_all(
    const float* __restrict__ face, const float* __restrict__ ner,
    unsigned short* __restrict__ face_bf, unsigned short* __restrict__ ner_bf,
    float* __restrict__ mask) {
  const int gw = blockIdx.x * 4 + (threadIdx.x >> 6);
  const int lane = threadIdx.x & 63;
  const bool isFace = gw < M_TOT;
  const int row = isFace ? gw : gw - M_TOT;
  const float* src = (isFace ? face : ner) + (size_t)row * DIM_D;
  unsigned short* dst = (isFace ? face_bf : ner_bf) + (size_t)row * DIM_D;

  const float4 f0 = ((const float4*)src)[lane * 2];
  const float4 f1 = ((const float4*)src)[lane * 2 + 1];
  short8v o;
  o[0] = (short)f2bf(f0.x); o[1] = (short)f2bf(f0.y);
  o[2] = (short)f2bf(f0.z); o[3] = (short)f2bf(f0.w);
  o[4] = (short)f2bf(f1.x); o[5] = (short)f2bf(f1.y);
  o[6] = (short)f2bf(f1.z); o[7] = (short)f2bf(f1.w);
  *(short8v*)(dst + lane * 8) = o;

  if (isFace) {
    float fs = f0.x + f0.y + f0.z + f0.w + f1.x + f1.y + f1.z + f1.w;
#pragma unroll
    for (int off = 1; off < 64; off <<= 1) fs += __shfl_xor(fs, off);
    if (lane == 0) mask[row] = (fs != 0.0f) ? 1.0f : 0.0f;
  }
}

// ---------------------------------------------------------------------------
// 128x128 bf16 MFMA GEMM, BK=32, 4 waves (2x2), per-wave 64x64 = 4x4 frags.
// LDS: ring of 3 x (A 8KB + B 8KB) = 48 KB static. Staging 2 tiles ahead;
// per K-tile: issue STAGE(t+2), 8 ds_read_b128, 16 MFMA, vmcnt(4), s_barrier.
// Swizzle (r2-measured 0 conflicts): LDS slot s of row r holds global k-slot
// s ^ ((r>>1)&3); staged with pre-swizzled global source, linear LDS dst.
// ---------------------------------------------------------------------------
#define MFMA(A_, B_, C_) __builtin_amdgcn_mfma_f32_16x16x32_bf16(A_, B_, C_, 0, 0, 0)

#define GLDS(SRC, DSTOFF)                                                     \
  __builtin_amdgcn_global_load_lds(                                           \
      (const __attribute__((address_space(1))) void*)(SRC),                   \
      (__attribute__((address_space(3))) void*)(lds + (DSTOFF)), 16, 0, 0)

__global__ __launch_bounds__(256, 3) void grl_gemm128(
    const unsigned short* __restrict__ A, const unsigned short* __restrict__ Bn,
    float* __restrict__ S_all, float* __restrict__ pos,
    float* __restrict__ diagm) {
  __shared__ __align__(16) unsigned short lds[3 * 8192];  // 48 KB

  const int tid = threadIdx.x;
  const int lane = tid & 63;
  const int wid = tid >> 6;
  const int wr = wid >> 1;   // 0..1 (M)
  const int wc = wid & 1;    // 0..1 (N)
  // XCD-chunked swizzle: 2048 blocks, 8 XCDs, 256/chunk. Within a chunk,
  // by varies fastest -> each XCD re-reads the same 8 A-panels + all of B.
  const int bid = blockIdx.x;
  const int swz = (bid & 7) * 256 + (bid >> 3);
  const int bx = swz >> 5;   // 0..63
  const int by = swz & 31;   // 0..31
  const int m0 = bx * 128;
  const int n0 = by * 128;

  // ---- stager: 4 gload_lds per K-tile. instr covers 64 rows -------------
  // row = i*64 + wid*16 + (lane>>2), slot = lane&3;
  // source k-slot g = slot ^ ((row>>1)&3) = (lane&3) ^ ((lane>>3)&3).
  const int g = (lane & 3) ^ ((lane >> 3) & 3);
  const int sr = wid * 16 + (lane >> 2);   // 0..63
  const unsigned short* gA = A + (size_t)(m0 + sr) * DIM_D + g * 8;
  const unsigned short* gB = Bn + (size_t)(n0 + sr) * DIM_D + g * 8;
  const int lb0 = wid * 512;  // wave-uniform LDS base (shorts); HW adds lane*16B

#define STAGE(T)                                            \
  do {                                                      \
    const int bo_ = ((T) % 3) * 8192;                       \
    GLDS(gA + (T) * 32, bo_ + lb0);                         \
    GLDS(gA + (T) * 32 + 64 * DIM_D, bo_ + 2048 + lb0);     \
    GLDS(gB + (T) * 32, bo_ + 4096 + lb0);                  \
    GLDS(gB + (T) * 32 + 64 * DIM_D, bo_ + 6144 + lb0);     \
  } while (0)

  // ---- reader: frag row = base + (lane&15), k-slot = lane>>4, swizzled --
  const int fo = (lane & 15) * 32 + (((lane >> 4) ^ ((lane >> 1) & 3)) * 8);

  f32x4 acc[4][4];
#pragma unroll
  for (int i = 0; i < 4; ++i)
#pragma unroll
    for (int j = 0; j < 4; ++j) acc[i][j] = (f32x4){0.f, 0.f, 0.f, 0.f};

#define KBODY(T)                                                          \
  do {                                                                    \
    const unsigned short* Lb = lds + ((T) % 3) * 8192;                    \
    short8v a0 = *(const short8v*)(Lb + (wr * 64 + 0) * 32 + fo);         \
    short8v a1 = *(const short8v*)(Lb + (wr * 64 + 16) * 32 + fo);        \
    short8v a2 = *(const short8v*)(Lb + (wr * 64 + 32) * 32 + fo);        \
    short8v a3 = *(const short8v*)(Lb + (wr * 64 + 48) * 32 + fo);        \
    short8v b0 = *(const short8v*)(Lb + 4096 + (wc * 64 + 0) * 32 + fo);  \
    short8v b1 = *(const short8v*)(Lb + 4096 + (wc * 64 + 16) * 32 + fo); \
    short8v b2 = *(const short8v*)(Lb + 4096 + (wc * 64 + 32) * 32 + fo); \
    short8v b3 = *(const short8v*)(Lb + 4096 + (wc * 64 + 48) * 32 + fo); \
    acc[0][0] = MFMA(a0, b0, acc[0][0]);                                  \
    acc[0][1] = MFMA(a0, b1, acc[0][1]);                                  \
    acc[0][2] = MFMA(a0, b2, acc[0][2]);                                  \
    acc[0][3] = MFMA(a0, b3, acc[0][3]);                                  \
    acc[1][0] = MFMA(a1, b0, acc[1][0]);                                  \
    acc[1][1] = MFMA(a1, b1, acc[1][1]);                                  \
    acc[1][2] = MFMA(a1, b2, acc[1][2]);                                  \
    acc[1][3] = MFMA(a1, b3, acc[1][3]);                                  \
    acc[2][0] = MFMA(a2, b0, acc[2][0]);                                  \
    acc[2][1] = MFMA(a2, b1, acc[2][1]);                                  \
    acc[2][2] = MFMA(a2, b2, acc[2][2]);                                  \
    acc[2][3] = MFMA(a2, b3, acc[2][3]);                                  \
    acc[3][0] = MFMA(a3, b0, acc[3][0]);                                  \
    acc[3][1] = MFMA(a3, b1, acc[3][1]);                                  \
    acc[3][2] = MFMA(a3, b2, acc[3][2]);                                  \
    acc[3][3] = MFMA(a3, b3, acc[3][3]);                                  \
  } while (0)

  // ---- prologue: stage tiles 0,1 (8 loads); wait tile 0 (vmcnt 4) -------
  STAGE(0);
  STAGE(1);
  asm volatile("s_waitcnt vmcnt(4)" ::: "memory");
  __builtin_amdgcn_s_barrier();

  // ---- main loop: stage t+2, compute t, vmcnt(4) keeps 4 in flight ------
  for (int t = 0; t < 14; ++t) {
    STAGE(t + 2);
    KBODY(t);
    asm volatile("s_waitcnt vmcnt(4)" ::: "memory");  // tile t+1 landed
    __builtin_amdgcn_s_barrier();
  }
  // ---- tail ------------------------------------------------------------
  KBODY(14);
  asm volatile("s_waitcnt vmcnt(0)" ::: "memory");    // tile 15 landed
  __builtin_amdgcn_s_barrier();
  KBODY(15);

  // ---- fused relu + (==1 -> 0) + per-thread row sums --------------------
  // C/D layout: col = lane&15 (n), row(frag) = (lane>>4)*4 + reg
  float rs[4][4];  // [mi][reg]
#pragma unroll
  for (int mi = 0; mi < 4; ++mi)
#pragma unroll
    for (int r = 0; r < 4; ++r) rs[mi][r] = 0.0f;
#pragma unroll
  for (int mi = 0; mi < 4; ++mi)
#pragma unroll
    for (int ni = 0; ni < 4; ++ni)
#pragma unroll
      for (int r = 0; r < 4; ++r) {
        float v = acc[mi][ni][r];
        v = v > 0.0f ? v : 0.0f;
        v = (v == 1.0f) ? 0.0f : v;
        rs[mi][r] += v;
      }
#pragma unroll
  for (int mi = 0; mi < 4; ++mi)
#pragma unroll
    for (int r = 0; r < 4; ++r) {
      float s = rs[mi][r];
      s += __shfl_xor(s, 1);
      s += __shfl_xor(s, 2);
      s += __shfl_xor(s, 4);
      s += __shfl_xor(s, 8);
      if ((lane & 15) == 0)
        atomicAdd(&S_all[m0 + wr * 64 + mi * 16 + (lane >> 4) * 4 + r], s);
    }

  // ---- fused diagonal (blocks with by == bx>>1 only) --------------------
  if (by == (bx >> 1)) {
#pragma unroll
    for (int mi = 0; mi < 4; ++mi) {
      const int R0 = m0 + wr * 64 + mi * 16;  // rows R0..R0+15 share b_
      const int tc = ((R0 >> 5) << 4) - n0;   // in [0,128)
      if ((tc >> 6) == wc) {
        const int dn = (tc >> 4) & 3;
#pragma unroll
        for (int ni = 0; ni < 4; ++ni)
          if (ni == dn) {
#pragma unroll
            for (int r = 0; r < 4; ++r) {
              float v = acc[mi][ni][r];
              v = v > 0.0f ? v : 0.0f;
              float vm = (v == 1.0f) ? 0.0f : v;
              float ps = v, ds = vm;
              ps += __shfl_xor(ps, 1); ds += __shfl_xor(ds, 1);
              ps += __shfl_xor(ps, 2); ds += __shfl_xor(ds, 2);
              ps += __shfl_xor(ps, 4); ds += __shfl_xor(ds, 4);
              ps += __shfl_xor(ps, 8); ds += __shfl_xor(ds, 8);
              if ((lane & 15) == 0) {
                const int R = R0 + (lane >> 4) * 4 + r;
                pos[R] = ps;
                diagm[R] = ds;
              }
            }
          }
      }
    }
  }
}

// ---------------------------------------------------------------------------
// Finalize: rank + global sum. Single block, 1024 threads.
// ---------------------------------------------------------------------------
__global__ __launch_bounds__(1024) void grl_final(
    const float* __restrict__ S_all, const float* __restrict__ diagm,
    const float* __restrict__ pos, const float* __restrict__ mask,
    float* __restrict__ out) {
  __shared__ float red[16];
  const int lane = threadIdx.x & 63;
  const int wv = threadIdx.x >> 6;
  float s = 0.0f;
  for (int r = threadIdx.x; r < M_TOT; r += 1024) {
    const float neg = (S_all[r] - diagm[r]) / 255.0f;  // 255 + 1e-8 == 255.0f
    float rank = neg - pos[r] + 0.2f;
    rank = rank > 0.0f ? rank : 0.0f;
    s += rank * mask[r];
  }
#pragma unroll
  for (int off = 1; off < 64; off <<= 1) s += __shfl_xor(s, off);
  if (lane == 0) red[wv] = s;
  __syncthreads();
  if (threadIdx.x == 0) {
    float t = 0.0f;
#pragma unroll
    for (int i = 0; i < 16; ++i) t += red[i];
    out[0] = t / 256.0f;  // BETA * sum / B
  }
}

// ---------------------------------------------------------------------------
extern "C" void kernel_launch(void* const* d_in, const int* in_sizes, int n_in,
                              void* d_out, int out_size, void* d_ws, size_t ws_size,
                              hipStream_t stream) {
  const float* face = (const float*)d_in[0];
  const float* ner = (const float*)d_in[1];

  unsigned short* face_bf = (unsigned short*)d_ws;
  unsigned short* ner_bf = face_bf + (size_t)M_TOT * DIM_D;
  float* S_all = (float*)(ner_bf + (size_t)N_TOT * DIM_D);
  float* diagm = S_all + M_TOT;
  float* pos = diagm + M_TOT;
  float* mask = pos + M_TOT;

  hipMemsetAsync(S_all, 0, M_TOT * sizeof(float), stream);
  cvt_all<<<(M_TOT + N_TOT) / 4, 256, 0, stream>>>(face, ner, face_bf, ner_bf,
                                                   mask);
  grl_gemm128<<<(M_TOT / 128) * (N_TOT / 128), 256, 0, stream>>>(
      face_bf, ner_bf, S_all, pos, diagm);
  grl_final<<<1, 1024, 0, stream>>>(S_all, diagm, pos, mask, (float*)d_out);
}

// Round 8
// 69.753 us; speedup vs baseline: 1.0701x; 1.0701x over previous
//
#include <hip/hip_runtime.h>

// B=256, F=32, N=16, D=512
//   sims[b,f,c,n] = relu(face[b,f]·ner[c,n])      (8192 x 4096 NT GEMM, K=512)
//   S_all[b,f]    = sum_{c,n} masked(sims)        (masked: ==1.0 -> 0)
//   pos[b,f]      = sum_n sims[b,f,b,n]           (unmasked diagonal)
//   diag_m[b,f]   = sum_n masked(sims[b,f,b,n])
//   loss = sum(relu((S_all-diag_m)/255 - pos + 0.2) * face_mask) / 256
//
// Round 8: m201-style 8-phase 256x256 template. BK=64, 8 waves (2M x 4N,
// wave tile 128x64), 2 K-tile LDS double-buffer (128 KiB). Per phase:
// {4-8 ds_read_b128 -> stage 1 half-tile -> s_barrier -> setprio(1) ->
// 16 MFMA -> setprio(0) -> s_barrier}; vmcnt(0) only at K-tile boundaries
// (last load issued >= 1 full MFMA phase earlier). 8-slot XOR swizzle
// (slot ^= row&7) staged via pre-swizzled global source (rule #21).
// Fused rowsum + diagonal extraction epilogue; merged cvt+mask kernel.

#define DIM_D 512
#define M_TOT 8192
#define N_TOT 4096

typedef __attribute__((ext_vector_type(8))) short short8v;
typedef __attribute__((ext_vector_type(4))) float f32x4;

__device__ __forceinline__ unsigned short f2bf(float f) {
  unsigned int u = __builtin_bit_cast(unsigned int, f);
  u += 0x7fffu + ((u >> 16) & 1u);
  return (unsigned short)(u >> 16);
}

// ---------------------------------------------------------------------------
// Merged cvt: face+ner fp32 -> bf16, plus face_mask (fp32 row-sum != 0).
// ---------------------------------------------------------------------------
__global__ __launch_bounds__(256) void cvt_all(
    const float* __restrict__ face, const float* __restrict__ ner,
    unsigned short* __restrict__ face_bf, unsigned short* __restrict__ ner_bf,
    float* __restrict__ mask) {
  const int gw = blockIdx.x * 4 + (threadIdx.x >> 6);
  const int lane = threadIdx.x & 63;
  const bool isFace = gw < M_TOT;
  const int row = isFace ? gw : gw - M_TOT;
  const float* src = (isFace ? face : ner) + (size_t)row * DIM_D;
  unsigned short* dst = (isFace ? face_bf : ner_bf) + (size_t)row * DIM_D;

  const float4 f0 = ((const float4*)src)[lane * 2];
  const float4 f1 = ((const float4*)src)[lane * 2 + 1];
  short8v o;
  o[0] = (short)f2bf(f0.x); o[1] = (short)f2bf(f0.y);
  o[2] = (short)f2bf(f0.z); o[3] = (short)f2bf(f0.w);
  o[4] = (short)f2bf(f1.x); o[5] = (short)f2bf(f1.y);
  o[6] = (short)f2bf(f1.z); o[7] = (short)f2bf(f1.w);
  *(short8v*)(dst + lane * 8) = o;

  if (isFace) {
    float fs = f0.x + f0.y + f0.z + f0.w + f1.x + f1.y + f1.z + f1.w;
#pragma unroll
    for (int off = 1; off < 64; off <<= 1) fs += __shfl_xor(fs, off);
    if (lane == 0) mask[row] = (fs != 0.0f) ? 1.0f : 0.0f;
  }
}

// ---------------------------------------------------------------------------
// 256x256 8-phase GEMM.
// LDS (shorts): buf b (b = T&1) at b*32768; A at +0 (256 rows x 8 slots x 8),
// B at +16384. slot s of row r holds global k-slot s ^ (r&7).
// K-tile T has 4 half-tiles {A-h0, A-h1, B-h0, B-h1}, 16 KB each, staged one
// per phase of K-tile T-1 (2 x global_load_lds w=16 per wave each).
// Phase Q of T: mh = Q&1 (A quarter), ks = Q>>1 (K half). B frags read at
// Q=0,2 (reused at Q=1,3). 16 MFMA per phase: mi = mh*4+f x ni 0..3.
// ---------------------------------------------------------------------------
#define MFMA(A_, B_, C_) __builtin_amdgcn_mfma_f32_16x16x32_bf16(A_, B_, C_, 0, 0, 0)

#define GLDS(SRC, DSTOFF)                                                     \
  __builtin_amdgcn_global_load_lds(                                           \
      (const __attribute__((address_space(1))) void*)(SRC),                   \
      (__attribute__((address_space(3))) void*)(lds + (DSTOFF)), 16, 0, 0)

__global__ __launch_bounds__(512, 2) void grl_gemm256(
    const unsigned short* __restrict__ A, const unsigned short* __restrict__ Bn,
    float* __restrict__ S_all, float* __restrict__ pos,
    float* __restrict__ diagm) {
  extern __shared__ unsigned short lds[];  // 2 x (A 16384 + B 16384) shorts

  const int tid = threadIdx.x;
  const int lane = tid & 63;
  const int wid = tid >> 6;
  const int wr = wid >> 2;     // 0..1 (M half)
  const int wc = wid & 3;      // 0..3 (N quarter)
  const int by = blockIdx.x;   // 0..15 (N)
  const int bx = blockIdx.y;   // 0..31 (M)
  const int m0 = bx * 256;
  const int n0 = by * 256;

  // ---- stager: per half-tile, wave w does 2 loads (i=0,1), 8 rows each --
  // row = h*128 + w*16 + i*8 + (lane>>3); slot = lane&7 holds global k-slot
  // g = (lane&7) ^ (lane>>3)  (since row&7 == lane>>3).
  const int g = (lane & 7) ^ (lane >> 3);
  const unsigned short* gA = A + (size_t)(m0 + wid * 16 + (lane >> 3)) * DIM_D + g * 8;
  const unsigned short* gB = Bn + (size_t)(n0 + wid * 16 + (lane >> 3)) * DIM_D + g * 8;
  const int wdst = wid * 1024;  // (wid*16 rows)*64 shorts/row, wave-uniform

#define STAGE_HALF(MATB, H, T)                                               \
  do {                                                                       \
    const unsigned short* gp_ = (MATB) ? gB : gA;                            \
    const int d0_ = ((T)&1) * 32768 + ((MATB) ? 16384 : 0) + (H)*8192 + wdst;\
    GLDS(gp_ + (size_t)(H)*65536 + (T)*64, d0_);                             \
    GLDS(gp_ + (size_t)(H)*65536 + 4096 + (T)*64, d0_ + 512);                \
  } while (0)

  // ---- reader: frag row = base + (lane&15); k-slot = ks*4 + (lane>>4),
  // swizzled by row&7 == lane&7.
  const int rrow = (lane & 15) * 64;
  const int s0 = ((lane >> 4) ^ (lane & 7)) * 8;  // ks=0
  const int s1 = s0 ^ 32;                         // ks=1

  f32x4 acc[8][4];
#pragma unroll
  for (int i = 0; i < 8; ++i)
#pragma unroll
    for (int j = 0; j < 4; ++j) acc[i][j] = (f32x4){0.f, 0.f, 0.f, 0.f};

  short8v a0, a1, a2, a3, b0, b1, b2, b3;

#define PH(T, Q)                                                             \
  do {                                                                       \
    const int bb_ = ((T)&1) * 32768;                                         \
    const int sk_ = ((Q) >> 1) ? s1 : s0;                                    \
    const unsigned short* Ab_ =                                              \
        lds + bb_ + (wr * 128 + ((Q)&1) * 64) * 64 + rrow + sk_;             \
    a0 = *(const short8v*)(Ab_);                                             \
    a1 = *(const short8v*)(Ab_ + 1024);                                      \
    a2 = *(const short8v*)(Ab_ + 2048);                                      \
    a3 = *(const short8v*)(Ab_ + 3072);                                      \
    if (((Q)&1) == 0) {                                                      \
      const unsigned short* Bb_ = lds + bb_ + 16384 + wc * 4096 + rrow + sk_;\
      b0 = *(const short8v*)(Bb_);                                           \
      b1 = *(const short8v*)(Bb_ + 1024);                                    \
      b2 = *(const short8v*)(Bb_ + 2048);                                    \
      b3 = *(const short8v*)(Bb_ + 3072);                                    \
    }                                                                        \
    if ((T) < 7) STAGE_HALF((Q) >> 1, (Q)&1, (T) + 1);                       \
    __builtin_amdgcn_s_barrier();                                            \
    __builtin_amdgcn_s_setprio(1);                                           \
    acc[((Q)&1) * 4 + 0][0] = MFMA(a0, b0, acc[((Q)&1) * 4 + 0][0]);         \
    acc[((Q)&1) * 4 + 0][1] = MFMA(a0, b1, acc[((Q)&1) * 4 + 0][1]);         \
    acc[((Q)&1) * 4 + 0][2] = MFMA(a0, b2, acc[((Q)&1) * 4 + 0][2]);         \
    acc[((Q)&1) * 4 + 0][3] = MFMA(a0, b3, acc[((Q)&1) * 4 + 0][3]);         \
    acc[((Q)&1) * 4 + 1][0] = MFMA(a1, b0, acc[((Q)&1) * 4 + 1][0]);         \
    acc[((Q)&1) * 4 + 1][1] = MFMA(a1, b1, acc[((Q)&1) * 4 + 1][1]);         \
    acc[((Q)&1) * 4 + 1][2] = MFMA(a1, b2, acc[((Q)&1) * 4 + 1][2]);         \
    acc[((Q)&1) * 4 + 1][3] = MFMA(a1, b3, acc[((Q)&1) * 4 + 1][3]);         \
    acc[((Q)&1) * 4 + 2][0] = MFMA(a2, b0, acc[((Q)&1) * 4 + 2][0]);         \
    acc[((Q)&1) * 4 + 2][1] = MFMA(a2, b1, acc[((Q)&1) * 4 + 2][1]);         \
    acc[((Q)&1) * 4 + 2][2] = MFMA(a2, b2, acc[((Q)&1) * 4 + 2][2]);         \
    acc[((Q)&1) * 4 + 2][3] = MFMA(a2, b3, acc[((Q)&1) * 4 + 2][3]);         \
    acc[((Q)&1) * 4 + 3][0] = MFMA(a3, b0, acc[((Q)&1) * 4 + 3][0]);         \
    acc[((Q)&1) * 4 + 3][1] = MFMA(a3, b1, acc[((Q)&1) * 4 + 3][1]);         \
    acc[((Q)&1) * 4 + 3][2] = MFMA(a3, b2, acc[((Q)&1) * 4 + 3][2]);         \
    acc[((Q)&1) * 4 + 3][3] = MFMA(a3, b3, acc[((Q)&1) * 4 + 3][3]);         \
    __builtin_amdgcn_s_setprio(0);                                           \
    if ((Q) == 3) asm volatile("s_waitcnt vmcnt(0)" ::: "memory");           \
    __builtin_amdgcn_s_barrier();                                            \
  } while (0)

  // ---- prologue: stage K-tile 0 fully, drain, barrier -------------------
  STAGE_HALF(0, 0, 0);
  STAGE_HALF(0, 1, 0);
  STAGE_HALF(1, 0, 0);
  STAGE_HALF(1, 1, 0);
  asm volatile("s_waitcnt vmcnt(0)" ::: "memory");
  __builtin_amdgcn_s_barrier();

  // ---- main loop: K-tile T (4 phases); T+1 staged 1 half-tile/phase -----
  for (int t = 0; t < 8; ++t) {
    PH(t, 0);
    PH(t, 1);
    PH(t, 2);
    PH(t, 3);
  }

  // ---- fused relu + (==1 -> 0) + per-thread row sums --------------------
  // C/D layout: col = lane&15 (n), row(frag) = (lane>>4)*4 + reg
  float rs[8][4];
#pragma unroll
  for (int mi = 0; mi < 8; ++mi)
#pragma unroll
    for (int r = 0; r < 4; ++r) rs[mi][r] = 0.0f;
#pragma unroll
  for (int mi = 0; mi < 8; ++mi)
#pragma unroll
    for (int ni = 0; ni < 4; ++ni)
#pragma unroll
      for (int r = 0; r < 4; ++r) {
        float v = acc[mi][ni][r];
        v = v > 0.0f ? v : 0.0f;
        v = (v == 1.0f) ? 0.0f : v;
        rs[mi][r] += v;
      }
#pragma unroll
  for (int mi = 0; mi < 8; ++mi)
#pragma unroll
    for (int r = 0; r < 4; ++r) {
      float s = rs[mi][r];
      s += __shfl_xor(s, 1);
      s += __shfl_xor(s, 2);
      s += __shfl_xor(s, 4);
      s += __shfl_xor(s, 8);
      if ((lane & 15) == 0)
        atomicAdd(&S_all[m0 + wr * 128 + mi * 16 + (lane >> 4) * 4 + r], s);
    }

  // ---- fused diagonal (blocks with by == bx>>1 only) --------------------
  if (by == (bx >> 1)) {
#pragma unroll
    for (int mi = 0; mi < 8; ++mi) {
      const int R0 = m0 + wr * 128 + mi * 16;  // rows R0..R0+15 share b_
      const int tc = ((R0 >> 5) << 4) - n0;    // diag col offset in tile
      if ((tc >> 6) == wc) {
        const int dn = (tc >> 4) & 3;
#pragma unroll
        for (int ni = 0; ni < 4; ++ni)
          if (ni == dn) {
#pragma unroll
            for (int r = 0; r < 4; ++r) {
              float v = acc[mi][ni][r];
              v = v > 0.0f ? v : 0.0f;
              float vm = (v == 1.0f) ? 0.0f : v;
              float ps = v, ds = vm;
              ps += __shfl_xor(ps, 1); ds += __shfl_xor(ds, 1);
              ps += __shfl_xor(ps, 2); ds += __shfl_xor(ds, 2);
              ps += __shfl_xor(ps, 4); ds += __shfl_xor(ds, 4);
              ps += __shfl_xor(ps, 8); ds += __shfl_xor(ds, 8);
              if ((lane & 15) == 0) {
                const int R = R0 + (lane >> 4) * 4 + r;
                pos[R] = ps;
                diagm[R] = ds;
              }
            }
          }
      }
    }
  }
}

// ---------------------------------------------------------------------------
// Finalize: rank + global sum. Single block, 1024 threads.
// ---------------------------------------------------------------------------
__global__ __launch_bounds__(1024) void grl_final(
    const float* __restrict__ S_all, const float* __restrict__ diagm,
    const float* __restrict__ pos, const float* __restrict__ mask,
    float* __restrict__ out) {
  __shared__ float red[16];
  const int lane = threadIdx.x & 63;
  const int wv = threadIdx.x >> 6;
  float s = 0.0f;
  for (int r = threadIdx.x; r < M_TOT; r += 1024) {
    const float neg = (S_all[r] - diagm[r]) / 255.0f;  // 255 + 1e-8 == 255.0f
    float rank = neg - pos[r] + 0.2f;
    rank = rank > 0.0f ? rank : 0.0f;
    s += rank * mask[r];
  }
#pragma unroll
  for (int off = 1; off < 64; off <<= 1) s += __shfl_xor(s, off);
  if (lane == 0) red[wv] = s;
  __syncthreads();
  if (threadIdx.x == 0) {
    float t = 0.0f;
#pragma unroll
    for (int i = 0; i < 16; ++i) t += red[i];
    out[0] = t / 256.0f;  // BETA * sum / B
  }
}

// ---------------------------------------------------------------------------
extern "C" void kernel_launch(void* const* d_in, const int* in_sizes, int n_in,
                              void* d_out, int out_size, void* d_ws, size_t ws_size,
                              hipStream_t stream) {
  const float* face = (const float*)d_in[0];
  const float* ner = (const float*)d_in[1];

  unsigned short* face_bf = (unsigned short*)d_ws;
  unsigned short* ner_bf = face_bf + (size_t)M_TOT * DIM_D;
  float* S_all = (float*)(ner_bf + (size_t)N_TOT * DIM_D);
  float* diagm = S_all + M_TOT;
  float* pos = diagm + M_TOT;
  float* mask = pos + M_TOT;

  hipFuncSetAttribute((const void*)grl_gemm256,
                      hipFuncAttributeMaxDynamicSharedMemorySize, 131072);

  hipMemsetAsync(S_all, 0, M_TOT * sizeof(float), stream);
  cvt_all<<<(M_TOT + N_TOT) / 4, 256, 0, stream>>>(face, ner, face_bf, ner_bf,
                                                   mask);
  grl_gemm256<<<dim3(N_TOT / 256, M_TOT / 256), 512, 131072, stream>>>(
      face_bf, ner_bf, S_all, pos, diagm);
  grl_final<<<1, 1024, 0, stream>>>(S_all, diagm, pos, mask, (float*)d_out);
}